// Round 5
// baseline (187.362 us; speedup 1.0000x reference)
//
#include <hip/hip_runtime.h>
#include <math.h>

#define BB 8
#define NN 512
#define DD 512
#define DKK 64
#define NC 192                  // 3*DK columns of W_qkv
#define CHN (BB * DKK * NN)     // 262144 floats per Q (or K or V) image

// (1/sqrt(64)) * log2(e) : fold softmax scale into exp2 domain
#define T_FACT 0.18033688011112042591999058f

#if defined(__has_builtin)
#if __has_builtin(__builtin_amdgcn_exp2f)
#define EXP2F(x) __builtin_amdgcn_exp2f(x)
#else
#define EXP2F(x) exp2f(x)
#endif
#else
#define EXP2F(x) exp2f(x)
#endif

// -------------------------------------------------------------------------
// Kernel 1: QKV projection, weights on the SCALAR path.
// Grid (32 cpair, 8 b, 2 nhalf), 256 threads; thread owns row n and
// computes q,k,v for channels {c0, c0+1}.
//  - W addresses are block/loop-uniform -> compiler emits s_load; weight
//    operands ride in SGPRs (no LDS pipe, no VALU cost beyond the FMA).
//  - X row streamed 32 floats (one full 128-B line) per iteration: every
//    fetched line fully consumed in-iteration -> no L1 retention needed,
//    no over-fetch. L2 traffic = 32 cpair * 8 MB = 256 MB (~8 us).
// Output qkv[which][b][c][n] (channel-major for kernels 2/3).
// -------------------------------------------------------------------------
__global__ __launch_bounds__(256) void qkv_proj(const float* __restrict__ X,
                                                const float* __restrict__ W,
                                                float* __restrict__ qkv) {
    const int t  = threadIdx.x;
    const int c0 = blockIdx.x * 2;
    const int b  = blockIdx.y;
    const int n  = blockIdx.z * 256 + t;

    const float* xrow = X + ((size_t)(b * NN + n)) * DD;

    float q0 = 0.f, k0 = 0.f, v0 = 0.f;
    float q1 = 0.f, k1 = 0.f, v1 = 0.f;

    for (int d0 = 0; d0 < DD; d0 += 32) {
        float x[32];
        #pragma unroll
        for (int i = 0; i < 8; ++i)
            *(float4*)&x[4 * i] = *(const float4*)(xrow + d0 + 4 * i);
        #pragma unroll
        for (int i = 0; i < 32; ++i) {
            const float* wr = W + (size_t)(d0 + i) * NC + c0;  // uniform addr
            const float wq0 = wr[0],   wq1 = wr[1];
            const float wk0 = wr[64],  wk1 = wr[65];
            const float wv0 = wr[128], wv1 = wr[129];
            q0 = fmaf(x[i], wq0, q0);  q1 = fmaf(x[i], wq1, q1);
            k0 = fmaf(x[i], wk0, k0);  k1 = fmaf(x[i], wk1, k1);
            v0 = fmaf(x[i], wv0, v0);  v1 = fmaf(x[i], wv1, v1);
        }
    }

    // qkv[w][b][c][n], coalesced across t
    const size_t base0 = ((size_t)(b * DKK + c0)) * NN + n;
    const size_t base1 = base0 + NN;  // c0+1
    qkv[base0]           = q0;  qkv[base1]           = q1;
    qkv[CHN + base0]     = k0;  qkv[CHN + base1]     = k1;
    qkv[2 * CHN + base0] = v0;  qkv[2 * CHN + base1] = v1;
}

// -------------------------------------------------------------------------
// Kernel 2: per-(b,c) rank-1 softmax attention. 512 blocks (one per
// channel), 256 threads, 2 n per thread (each k/v b128 read feeds 2 rows).
// Stable max via block-reduced kmax/kmin (t*kmax if t>0 else t*kmin).
// -------------------------------------------------------------------------
__global__ __launch_bounds__(256) void attn(const float* __restrict__ qkv,
                                            float* __restrict__ sa_t) {
    __shared__ float kl[NN];
    __shared__ float vl[NN];
    __shared__ float rmax[4], rmin[4];

    const int tid = threadIdx.x;
    const size_t chan = (size_t)blockIdx.x * NN;
    const float* qp = qkv + chan;
    const float* kp = qkv + CHN + chan;
    const float* vp = qkv + 2 * CHN + chan;

    if (tid < 128) ((float4*)kl)[tid]       = ((const float4*)kp)[tid];
    else           ((float4*)vl)[tid - 128] = ((const float4*)vp)[tid - 128];
    __syncthreads();

    float mx = fmaxf(kl[tid], kl[tid + 256]);
    float mn = fminf(kl[tid], kl[tid + 256]);
    #pragma unroll
    for (int off = 32; off > 0; off >>= 1) {
        mx = fmaxf(mx, __shfl_down(mx, off, 64));
        mn = fminf(mn, __shfl_down(mn, off, 64));
    }
    if ((tid & 63) == 0) { rmax[tid >> 6] = mx; rmin[tid >> 6] = mn; }
    __syncthreads();
    const float kmax = fmaxf(fmaxf(rmax[0], rmax[1]), fmaxf(rmax[2], rmax[3]));
    const float kmin = fminf(fminf(rmin[0], rmin[1]), fminf(rmin[2], rmin[3]));

    const float t0 = qp[tid] * T_FACT;
    const float t1 = qp[tid + 256] * T_FACT;
    const float M0 = t0 > 0.f ? t0 * kmax : t0 * kmin;
    const float M1 = t1 > 0.f ? t1 * kmax : t1 * kmin;

    float sw0 = 0.f, sv0 = 0.f, sw1 = 0.f, sv1 = 0.f;
    const float4* k4 = (const float4*)kl;
    const float4* v4 = (const float4*)vl;
    #pragma unroll 2
    for (int j = 0; j < NN / 4; ++j) {
        const float4 kk = k4[j];
        const float4 vv = v4[j];
        const float ke[4] = {kk.x, kk.y, kk.z, kk.w};
        const float ve[4] = {vv.x, vv.y, vv.z, vv.w};
        #pragma unroll
        for (int e = 0; e < 4; ++e) {
            const float w0 = EXP2F(fmaf(t0, ke[e], -M0));
            sw0 += w0;
            sv0 = fmaf(w0, ve[e], sv0);
            const float w1 = EXP2F(fmaf(t1, ke[e], -M1));
            sw1 += w1;
            sv1 = fmaf(w1, ve[e], sv1);
        }
    }
    sa_t[chan + tid]       = sv0 / sw0;
    sa_t[chan + tid + 256] = sv1 / sw1;
}

// -------------------------------------------------------------------------
// Kernel 3: out = SA(4096x64) @ Wo(64x512). sa_t is [b][c][n] (K-major
// per b). 256 threads, 64x64 tile, 4x4 micro-tile, float4 stores.
// -------------------------------------------------------------------------
__global__ __launch_bounds__(256) void out_gemm(const float* __restrict__ sa_t,
                                                const float* __restrict__ Wo,
                                                float* __restrict__ out) {
    __shared__ float As[64][68];  // As[c][n_local]
    __shared__ float Bs[64][68];  // Bs[c][d_local]

    const int tid  = threadIdx.x;
    const int row0 = blockIdx.x * 64;
    const int d0   = blockIdx.y * 64;
    const int b    = row0 >> 9;
    const int n0   = row0 & 511;

    const int f  = tid & 15;   // float4 index within 64
    const int r0 = tid >> 4;   // 0..15
    #pragma unroll
    for (int rr = 0; rr < 4; ++rr) {
        const int cidx = r0 + rr * 16;
        *(float4*)&As[cidx][4 * f] =
            *(const float4*)(sa_t + (size_t)(b * DKK + cidx) * NN + n0 + 4 * f);
        *(float4*)&Bs[cidx][4 * f] =
            *(const float4*)(Wo + (size_t)cidx * DD + d0 + 4 * f);
    }
    __syncthreads();

    const int tc = tid & 15;
    const int tr = tid >> 4;
    float acc[4][4] = {};
    #pragma unroll 8
    for (int k = 0; k < DKK; ++k) {
        const float4 a  = *(const float4*)&As[k][4 * tr];
        const float4 bv = *(const float4*)&Bs[k][4 * tc];
        const float av[4] = {a.x, a.y, a.z, a.w};
        const float be[4] = {bv.x, bv.y, bv.z, bv.w};
        #pragma unroll
        for (int i = 0; i < 4; ++i)
            #pragma unroll
            for (int j = 0; j < 4; ++j)
                acc[i][j] = fmaf(av[i], be[j], acc[i][j]);
    }

    float* op = out + ((size_t)(b * NN + n0)) * DD + d0;
    #pragma unroll
    for (int i = 0; i < 4; ++i) {
        const float4 v = {acc[i][0], acc[i][1], acc[i][2], acc[i][3]};
        *(float4*)(op + (size_t)(4 * tr + i) * DD + 4 * tc) = v;
    }
}

extern "C" void kernel_launch(void* const* d_in, const int* in_sizes, int n_in,
                              void* d_out, int out_size, void* d_ws, size_t ws_size,
                              hipStream_t stream) {
    const float* X    = (const float*)d_in[0];  // (8,512,512)
    const float* Wqkv = (const float*)d_in[1];  // (512,192)
    const float* Wo   = (const float*)d_in[2];  // (64,512)
    float* out = (float*)d_out;                 // (8,512,512)

    float* qkv  = (float*)d_ws;                 // [w][b][c][n], 3 MB
    float* sa_t = qkv + (size_t)3 * CHN;        // [b][c][n], 1 MB

    qkv_proj<<<dim3(32, BB, 2), 256, 0, stream>>>(X, Wqkv, qkv);
    attn<<<dim3(BB * DKK), 256, 0, stream>>>(qkv, sa_t);
    out_gemm<<<dim3(64, 8), 256, 0, stream>>>(sa_t, Wo, out);
}

// Round 6
// 119.350 us; speedup vs baseline: 1.5699x; 1.5699x over previous
//
#include <hip/hip_runtime.h>
#include <math.h>

#define BB 8
#define NN 512
#define DD 512
#define DKK 64
#define NC 192                    // 3*DK
#define PSZ (3 * BB * DKK * NN)   // 786432 floats per full QKV image
#define CHN (BB * DKK * NN)       // 262144 floats per Q (or K or V) image
#define NPART 4                   // split-K partials

// (1/sqrt(64)) * log2(e) : fold softmax scale into exp2 domain
#define T_FACT 0.18033688011112042591999058f

#if defined(__has_builtin)
#if __has_builtin(__builtin_amdgcn_exp2f)
#define EXP2F(x) __builtin_amdgcn_exp2f(x)
#else
#define EXP2F(x) exp2f(x)
#endif
#else
#define EXP2F(x) exp2f(x)
#endif

// -------------------------------------------------------------------------
// Kernel 1: QKV = X(4096x512) @ W(512x192), split-K z=4, channel-major
// partial output [z][which][b][c][n]. 64x64 tile, 4x4 micro-tile,
// REGISTER DOUBLE-BUFFER: next K-step's global loads are issued right
// after the post-stage barrier and consumed at the next stage, so global
// latency hides behind the FMA body instead of draining at each barrier.
// LDS: As[64][36] row-major (2-way-max conflicts = free),
//      Bs[32][68] (2-way b128 reads = free).
// -------------------------------------------------------------------------
__global__ __launch_bounds__(256) void qkv_gemm(const float* __restrict__ X,
                                                const float* __restrict__ W,
                                                float* __restrict__ outp_base,
                                                int kSteps) {
    __shared__ union {
        struct {
            float As[64][36];  // row-major: As[row][kk]
            float Bs[32][68];  // Bs[kk][col]
        } s;
        float Ct[64][68];      // transpose staging for epilogue
    } sm;

    const int tid   = threadIdx.x;
    const int row0  = blockIdx.x * 64;   // 64 rows of (b,n)-flattened X
    const int which = blockIdx.y;        // 0=Q, 1=K, 2=V
    const int c0    = which * 64;
    const int tc    = tid & 15;
    const int tr    = tid >> 4;

    // staging coords
    const int af = tid & 7;    // float4 index along k (0..7)
    const int ar = tid >> 3;   // 0..31 (two rows: ar, ar+32)
    const int bc = tid & 63;   // B col
    const int bk = tid >> 6;   // 0..3 (rows bk, bk+4, ... bk+28)

    float acc[4][4] = {};

    // prologue: load step 0 into registers
    float4 a0, a1;
    float breg[8];
    {
        const int k0 = blockIdx.z * kSteps * 32;
        a0 = *(const float4*)(X + (size_t)(row0 + ar) * DD + k0 + 4 * af);
        a1 = *(const float4*)(X + (size_t)(row0 + ar + 32) * DD + k0 + 4 * af);
        #pragma unroll
        for (int i = 0; i < 8; ++i)
            breg[i] = W[(size_t)(k0 + bk + 4 * i) * NC + c0 + bc];
    }

    for (int s = 0; s < kSteps; ++s) {
        // stage current registers -> LDS
        *(float4*)&sm.s.As[ar][4 * af]      = a0;
        *(float4*)&sm.s.As[ar + 32][4 * af] = a1;
        #pragma unroll
        for (int i = 0; i < 8; ++i)
            sm.s.Bs[bk + 4 * i][bc] = breg[i];
        __syncthreads();

        // issue next step's global loads (consumed at next stage)
        if (s + 1 < kSteps) {
            const int k0 = (blockIdx.z * kSteps + s + 1) * 32;
            a0 = *(const float4*)(X + (size_t)(row0 + ar) * DD + k0 + 4 * af);
            a1 = *(const float4*)(X + (size_t)(row0 + ar + 32) * DD + k0 + 4 * af);
            #pragma unroll
            for (int i = 0; i < 8; ++i)
                breg[i] = W[(size_t)(k0 + bk + 4 * i) * NC + c0 + bc];
        }

        // compute from LDS
        #pragma unroll 4
        for (int kk = 0; kk < 32; kk += 2) {
            float2 a[4];
            #pragma unroll
            for (int i = 0; i < 4; ++i)
                a[i] = *(const float2*)&sm.s.As[4 * tr + i][kk];
            const float4 b0 = *(const float4*)&sm.s.Bs[kk][4 * tc];
            const float4 b1 = *(const float4*)&sm.s.Bs[kk + 1][4 * tc];
            const float b0e[4] = {b0.x, b0.y, b0.z, b0.w};
            const float b1e[4] = {b1.x, b1.y, b1.z, b1.w};
            #pragma unroll
            for (int i = 0; i < 4; ++i) {
                #pragma unroll
                for (int j = 0; j < 4; ++j) {
                    acc[i][j] = fmaf(a[i].x, b0e[j], acc[i][j]);
                    acc[i][j] = fmaf(a[i].y, b1e[j], acc[i][j]);
                }
            }
        }
        __syncthreads();
    }

    // epilogue: transpose through LDS, write [z][which][b][c][n] coalesced
    #pragma unroll
    for (int i = 0; i < 4; ++i)
        #pragma unroll
        for (int j = 0; j < 4; ++j)
            sm.Ct[4 * tc + j][4 * tr + i] = acc[i][j];
    __syncthreads();

    const int b  = row0 >> 9;
    const int n0 = row0 & 511;
    float* outp = outp_base + (size_t)blockIdx.z * PSZ +
                  ((size_t)which * BB * DKK + (size_t)b * DKK) * NN;
    const int fl  = tid & 15;
    const int cl0 = tid >> 4;
    #pragma unroll
    for (int cc = 0; cc < 4; ++cc) {
        const int c_l = cl0 + cc * 16;
        const float4 v = *(const float4*)&sm.Ct[c_l][4 * fl];
        *(float4*)(outp + (size_t)c_l * NN + n0 + 4 * fl) = v;
    }
}

// -------------------------------------------------------------------------
// Kernel 2: per-(b,c) rank-1 softmax attention; split-K partials summed
// inline during staging. 512 blocks (one per channel), 256 threads,
// 2 n per thread (each k/v b128 LDS read feeds 2 rows).
// -------------------------------------------------------------------------
__global__ __launch_bounds__(256) void attn(const float* __restrict__ parts,
                                            float* __restrict__ sa_t,
                                            int npart) {
    __shared__ float kl[NN];
    __shared__ float vl[NN];
    __shared__ float rmax[4], rmin[4];

    const int tid = threadIdx.x;
    const size_t chan = (size_t)blockIdx.x * NN;

    // stage k (tid<128) / v (tid>=128): sum npart partials, one float4 each
    {
        const int slot  = tid & 127;
        const int which = tid >> 7;  // 0=k, 1=v
        const float4* src =
            (const float4*)(parts + (size_t)(which ? 2 : 1) * CHN + chan) + slot;
        float4 s = {0.f, 0.f, 0.f, 0.f};
        for (int p = 0; p < npart; ++p) {
            const float4 x = src[(size_t)p * (PSZ / 4)];
            s.x += x.x; s.y += x.y; s.z += x.z; s.w += x.w;
        }
        if (which) ((float4*)vl)[slot] = s;
        else       ((float4*)kl)[slot] = s;
    }
    __syncthreads();

    float mx = fmaxf(kl[tid], kl[tid + 256]);
    float mn = fminf(kl[tid], kl[tid + 256]);
    #pragma unroll
    for (int off = 32; off > 0; off >>= 1) {
        mx = fmaxf(mx, __shfl_down(mx, off, 64));
        mn = fminf(mn, __shfl_down(mn, off, 64));
    }
    if ((tid & 63) == 0) { rmax[tid >> 6] = mx; rmin[tid >> 6] = mn; }
    __syncthreads();
    const float kmax = fmaxf(fmaxf(rmax[0], rmax[1]), fmaxf(rmax[2], rmax[3]));
    const float kmin = fminf(fminf(rmin[0], rmin[1]), fminf(rmin[2], rmin[3]));

    float q0 = 0.f, q1 = 0.f;
    for (int p = 0; p < npart; ++p) {
        q0 += parts[(size_t)p * PSZ + chan + tid];
        q1 += parts[(size_t)p * PSZ + chan + tid + 256];
    }
    const float t0 = q0 * T_FACT;
    const float t1 = q1 * T_FACT;
    const float M0 = t0 > 0.f ? t0 * kmax : t0 * kmin;
    const float M1 = t1 > 0.f ? t1 * kmax : t1 * kmin;

    float sw0 = 0.f, sv0 = 0.f, sw1 = 0.f, sv1 = 0.f;
    const float4* k4 = (const float4*)kl;
    const float4* v4 = (const float4*)vl;
    #pragma unroll 2
    for (int j = 0; j < NN / 4; ++j) {
        const float4 kk = k4[j];
        const float4 vv = v4[j];
        const float ke[4] = {kk.x, kk.y, kk.z, kk.w};
        const float ve[4] = {vv.x, vv.y, vv.z, vv.w};
        #pragma unroll
        for (int e = 0; e < 4; ++e) {
            const float w0 = EXP2F(fmaf(t0, ke[e], -M0));
            sw0 += w0;
            sv0 = fmaf(w0, ve[e], sv0);
            const float w1 = EXP2F(fmaf(t1, ke[e], -M1));
            sw1 += w1;
            sv1 = fmaf(w1, ve[e], sv1);
        }
    }
    sa_t[chan + tid]       = sv0 / sw0;
    sa_t[chan + tid + 256] = sv1 / sw1;
}

// -------------------------------------------------------------------------
// Kernel 3: out = SA(4096x64) @ Wo(64x512). sa_t is [b][c][n] (K-major
// per b). 256 threads, 64x64 tile, 4x4 micro-tile, float4 stores.
// -------------------------------------------------------------------------
__global__ __launch_bounds__(256) void out_gemm(const float* __restrict__ sa_t,
                                                const float* __restrict__ Wo,
                                                float* __restrict__ out) {
    __shared__ float As[64][68];  // As[c][n_local]
    __shared__ float Bs[64][68];  // Bs[c][d_local]

    const int tid  = threadIdx.x;
    const int row0 = blockIdx.x * 64;
    const int d0   = blockIdx.y * 64;
    const int b    = row0 >> 9;
    const int n0   = row0 & 511;

    const int f  = tid & 15;   // float4 index within 64
    const int r0 = tid >> 4;   // 0..15
    #pragma unroll
    for (int rr = 0; rr < 4; ++rr) {
        const int cidx = r0 + rr * 16;
        *(float4*)&As[cidx][4 * f] =
            *(const float4*)(sa_t + (size_t)(b * DKK + cidx) * NN + n0 + 4 * f);
        *(float4*)&Bs[cidx][4 * f] =
            *(const float4*)(Wo + (size_t)cidx * DD + d0 + 4 * f);
    }
    __syncthreads();

    const int tc = tid & 15;
    const int tr = tid >> 4;
    float acc[4][4] = {};
    #pragma unroll 8
    for (int k = 0; k < DKK; ++k) {
        const float4 a  = *(const float4*)&As[k][4 * tr];
        const float4 bv = *(const float4*)&Bs[k][4 * tc];
        const float av[4] = {a.x, a.y, a.z, a.w};
        const float be[4] = {bv.x, bv.y, bv.z, bv.w};
        #pragma unroll
        for (int i = 0; i < 4; ++i)
            #pragma unroll
            for (int j = 0; j < 4; ++j)
                acc[i][j] = fmaf(av[i], be[j], acc[i][j]);
    }

    float* op = out + ((size_t)(b * NN + n0)) * DD + d0;
    #pragma unroll
    for (int i = 0; i < 4; ++i) {
        const float4 v = {acc[i][0], acc[i][1], acc[i][2], acc[i][3]};
        *(float4*)(op + (size_t)(4 * tr + i) * DD + 4 * tc) = v;
    }
}

extern "C" void kernel_launch(void* const* d_in, const int* in_sizes, int n_in,
                              void* d_out, int out_size, void* d_ws, size_t ws_size,
                              hipStream_t stream) {
    const float* X    = (const float*)d_in[0];  // (8,512,512)
    const float* Wqkv = (const float*)d_in[1];  // (512,192)
    const float* Wo   = (const float*)d_in[2];  // (64,512)
    float* out = (float*)d_out;                 // (8,512,512)

    int npart = NPART, kSteps = 16 / NPART;
    if (ws_size < (size_t)(NPART * PSZ + NN) * sizeof(float)) {
        npart = 1;
        kSteps = 16;
    }

    float* parts = (float*)d_ws;                 // npart * 3 MB partials
    float* sa_t  = parts + (size_t)npart * PSZ;  // 1 MB

    qkv_gemm<<<dim3(64, 3, npart), 256, 0, stream>>>(X, Wqkv, parts, kSteps);
    attn<<<dim3(BB * DKK), 256, 0, stream>>>(parts, sa_t, npart);
    out_gemm<<<dim3(64, 8), 256, 0, stream>>>(sa_t, Wo, out);
}

// Round 7
// 108.769 us; speedup vs baseline: 1.7226x; 1.0973x over previous
//
#include <hip/hip_runtime.h>
#include <math.h>

#define BB 8
#define NN 512
#define DD 512
#define DKK 64
#define NC 192                  // 3*DK
#define CHN (BB * DKK * NN)     // floats per Q (or K or V) image

// (1/sqrt(64)) * log2(e) : fold softmax scale into exp2 domain
#define T_FACT 0.18033688011112042591999058f

#if defined(__has_builtin)
#if __has_builtin(__builtin_amdgcn_exp2f)
#define EXP2F(x) __builtin_amdgcn_exp2f(x)
#else
#define EXP2F(x) exp2f(x)
#endif
#else
#define EXP2F(x) exp2f(x)
#endif

typedef short s8v  __attribute__((ext_vector_type(8)));
typedef float f32x4 __attribute__((ext_vector_type(4)));

static __device__ __forceinline__ unsigned short bf16_rne(float f) {
    unsigned u = __float_as_uint(f);
    unsigned r = 0x7FFFu + ((u >> 16) & 1u);
    return (unsigned short)((u + r) >> 16);
}
static __device__ __forceinline__ float bf16_f32(unsigned short h) {
    return __uint_as_float(((unsigned)h) << 16);
}

// -------------------------------------------------------------------------
// Kernel 1: QKV = X(4096x512) @ W(512x192) on the MFMA pipe via split-bf16:
// X = Xh + Xl (bf16 each), C = Xh*Wh + Xh*Wl + Xl*Wh (lo*lo dropped, ~1e-6).
// Grid (64 row-tiles, 3 which), 512 threads (8 waves). Block = 64x64 tile,
// BK=64. Wave = 16 rows x 32 cols (2 col-tiles), 12 MFMA/K-step.
// LDS: Xh/Xl[64][72] (row-major, k contig), Wh/Wl[64][72] = W^T (n-major,
// k contig); stride 72 halfwords = 144 B keeps b128 16B-aligned.
// Fragment layouts (HW-verified m89/m91/m120):
//   A: m=lane&15, k=quad*8+j ; B: n=lane&15, k=quad*8+j ;
//   C/D: col(n)=lane&15, row(m)=quad*4+reg.
// Epilogue transposes via LDS -> qkv[which][b][c][n] channel-major.
// -------------------------------------------------------------------------
__global__ __launch_bounds__(512) void qkv_mfma(const float* __restrict__ X,
                                                const float* __restrict__ W,
                                                float* __restrict__ qkv) {
    __shared__ union {
        struct {
            unsigned short Xh[64][72], Xl[64][72], Wh[64][72], Wl[64][72];
        } s;
        float Ct[64][72];
    } sm;

    const int tid   = threadIdx.x;
    const int row0  = blockIdx.x * 64;   // 64 rows of (b,n)-flattened X
    const int which = blockIdx.y;        // 0=Q, 1=K, 2=V
    const int c0    = which * 64;

    // staging coords: thread covers 8 contiguous k (X) / 8 k-rows (W)
    const int xr = tid >> 3;   // 0..63: X row / W channel
    const int xf = tid & 7;    // 0..7 : which 8-float chunk along k

    // compute coords
    const int wid  = tid >> 6;           // 0..7
    const int lane = tid & 63;
    const int m0   = (wid >> 1) * 16;    // wave's row base
    const int n0w  = (wid & 1) * 32;     // wave's col base (2 tiles of 16)
    const int lm   = lane & 15;
    const int quad = lane >> 4;

    f32x4 acc[2] = {{0.f, 0.f, 0.f, 0.f}, {0.f, 0.f, 0.f, 0.f}};

    // prefetch step 0
    float4 xa, xb;
    float  wreg[8];
    {
        const float* xp = X + (size_t)(row0 + xr) * DD + xf * 8;
        xa = *(const float4*)xp;
        xb = *(const float4*)(xp + 4);
        #pragma unroll
        for (int i = 0; i < 8; ++i)
            wreg[i] = W[(size_t)(xf * 8 + i) * NC + c0 + xr];
    }

    for (int s = 0; s < 8; ++s) {
        // convert current regs -> hi/lo bf16, store LDS
        {
            const float xe[8] = {xa.x, xa.y, xa.z, xa.w, xb.x, xb.y, xb.z, xb.w};
            s8v xh, xl, wh, wl;
            #pragma unroll
            for (int i = 0; i < 8; ++i) {
                const unsigned short h = bf16_rne(xe[i]);
                xh[i] = (short)h;
                xl[i] = (short)bf16_rne(xe[i] - bf16_f32(h));
                const unsigned short g = bf16_rne(wreg[i]);
                wh[i] = (short)g;
                wl[i] = (short)bf16_rne(wreg[i] - bf16_f32(g));
            }
            *(s8v*)&sm.s.Xh[xr][xf * 8] = xh;
            *(s8v*)&sm.s.Xl[xr][xf * 8] = xl;
            *(s8v*)&sm.s.Wh[xr][xf * 8] = wh;   // W^T: [channel][k]
            *(s8v*)&sm.s.Wl[xr][xf * 8] = wl;
        }
        __syncthreads();

        // prefetch next step's globals (hidden behind MFMA compute)
        if (s < 7) {
            const int k0 = (s + 1) * 64;
            const float* xp = X + (size_t)(row0 + xr) * DD + k0 + xf * 8;
            xa = *(const float4*)xp;
            xb = *(const float4*)(xp + 4);
            #pragma unroll
            for (int i = 0; i < 8; ++i)
                wreg[i] = W[(size_t)(k0 + xf * 8 + i) * NC + c0 + xr];
        }

        // compute: 2 k-subtiles of 32, 2 col-tiles, 3 MFMAs each
        #pragma unroll
        for (int ks = 0; ks < 2; ++ks) {
            const int ko = ks * 32 + quad * 8;
            const s8v ah = *(const s8v*)&sm.s.Xh[m0 + lm][ko];
            const s8v al = *(const s8v*)&sm.s.Xl[m0 + lm][ko];
            #pragma unroll
            for (int t = 0; t < 2; ++t) {
                const s8v bh = *(const s8v*)&sm.s.Wh[n0w + t * 16 + lm][ko];
                const s8v bl = *(const s8v*)&sm.s.Wl[n0w + t * 16 + lm][ko];
                acc[t] = __builtin_amdgcn_mfma_f32_16x16x32_bf16(ah, bh, acc[t], 0, 0, 0);
                acc[t] = __builtin_amdgcn_mfma_f32_16x16x32_bf16(ah, bl, acc[t], 0, 0, 0);
                acc[t] = __builtin_amdgcn_mfma_f32_16x16x32_bf16(al, bh, acc[t], 0, 0, 0);
            }
        }
        __syncthreads();
    }

    // epilogue: C^T via LDS (Ct[c][m]), then coalesced channel-major store
    #pragma unroll
    for (int t = 0; t < 2; ++t)
        #pragma unroll
        for (int r = 0; r < 4; ++r)
            sm.Ct[n0w + t * 16 + lm][m0 + quad * 4 + r] = acc[t][r];
    __syncthreads();

    const int b   = row0 >> 9;
    const int n0g = row0 & 511;
    float* outp = qkv + (size_t)which * CHN +
                  ((size_t)(b * DKK + xr)) * NN + n0g + xf * 8;
    *(float4*)outp       = *(const float4*)&sm.Ct[xr][xf * 8];
    *(float4*)(outp + 4) = *(const float4*)&sm.Ct[xr][xf * 8 + 4];
}

// -------------------------------------------------------------------------
// Kernel 2: per-(b,c) rank-1 softmax attention. 512 blocks (one per
// channel), 256 threads, 2 n per thread. Stable max via block-reduced
// kmax/kmin (M = t*kmax if t>0 else t*kmin).
// -------------------------------------------------------------------------
__global__ __launch_bounds__(256) void attn(const float* __restrict__ qkv,
                                            float* __restrict__ sa_t) {
    __shared__ float kl[NN];
    __shared__ float vl[NN];
    __shared__ float rmax[4], rmin[4];

    const int tid = threadIdx.x;
    const size_t chan = (size_t)blockIdx.x * NN;
    const float* qp = qkv + chan;
    const float* kp = qkv + CHN + chan;
    const float* vp = qkv + 2 * CHN + chan;

    if (tid < 128) ((float4*)kl)[tid]       = ((const float4*)kp)[tid];
    else           ((float4*)vl)[tid - 128] = ((const float4*)vp)[tid - 128];
    __syncthreads();

    float mx = fmaxf(kl[tid], kl[tid + 256]);
    float mn = fminf(kl[tid], kl[tid + 256]);
    #pragma unroll
    for (int off = 32; off > 0; off >>= 1) {
        mx = fmaxf(mx, __shfl_down(mx, off, 64));
        mn = fminf(mn, __shfl_down(mn, off, 64));
    }
    if ((tid & 63) == 0) { rmax[tid >> 6] = mx; rmin[tid >> 6] = mn; }
    __syncthreads();
    const float kmax = fmaxf(fmaxf(rmax[0], rmax[1]), fmaxf(rmax[2], rmax[3]));
    const float kmin = fminf(fminf(rmin[0], rmin[1]), fminf(rmin[2], rmin[3]));

    const float t0 = qp[tid] * T_FACT;
    const float t1 = qp[tid + 256] * T_FACT;
    const float M0 = t0 > 0.f ? t0 * kmax : t0 * kmin;
    const float M1 = t1 > 0.f ? t1 * kmax : t1 * kmin;

    float sw0 = 0.f, sv0 = 0.f, sw1 = 0.f, sv1 = 0.f;
    const float4* k4 = (const float4*)kl;
    const float4* v4 = (const float4*)vl;
    #pragma unroll 2
    for (int j = 0; j < NN / 4; ++j) {
        const float4 kk = k4[j];
        const float4 vv = v4[j];
        const float ke[4] = {kk.x, kk.y, kk.z, kk.w};
        const float ve[4] = {vv.x, vv.y, vv.z, vv.w};
        #pragma unroll
        for (int e = 0; e < 4; ++e) {
            const float w0 = EXP2F(fmaf(t0, ke[e], -M0));
            sw0 += w0;
            sv0 = fmaf(w0, ve[e], sv0);
            const float w1 = EXP2F(fmaf(t1, ke[e], -M1));
            sw1 += w1;
            sv1 = fmaf(w1, ve[e], sv1);
        }
    }
    sa_t[chan + tid]       = sv0 / sw0;
    sa_t[chan + tid + 256] = sv1 / sw1;
}

// -------------------------------------------------------------------------
// Kernel 3: out = SA(4096x64) @ Wo(64x512). sa_t is [b][c][n] (K-major
// per b). 256 threads, 64x64 tile, 4x4 micro-tile, float4 stores.
// -------------------------------------------------------------------------
__global__ __launch_bounds__(256) void out_gemm(const float* __restrict__ sa_t,
                                                const float* __restrict__ Wo,
                                                float* __restrict__ out) {
    __shared__ float As[64][68];  // As[c][n_local]
    __shared__ float Bs[64][68];  // Bs[c][d_local]

    const int tid  = threadIdx.x;
    const int row0 = blockIdx.x * 64;
    const int d0   = blockIdx.y * 64;
    const int b    = row0 >> 9;
    const int n0   = row0 & 511;

    const int f  = tid & 15;   // float4 index within 64
    const int r0 = tid >> 4;   // 0..15
    #pragma unroll
    for (int rr = 0; rr < 4; ++rr) {
        const int cidx = r0 + rr * 16;
        *(float4*)&As[cidx][4 * f] =
            *(const float4*)(sa_t + (size_t)(b * DKK + cidx) * NN + n0 + 4 * f);
        *(float4*)&Bs[cidx][4 * f] =
            *(const float4*)(Wo + (size_t)cidx * DD + d0 + 4 * f);
    }
    __syncthreads();

    const int tc = tid & 15;
    const int tr = tid >> 4;
    float acc[4][4] = {};
    #pragma unroll 8
    for (int k = 0; k < DKK; ++k) {
        const float4 a  = *(const float4*)&As[k][4 * tr];
        const float4 bv = *(const float4*)&Bs[k][4 * tc];
        const float av[4] = {a.x, a.y, a.z, a.w};
        const float be[4] = {bv.x, bv.y, bv.z, bv.w};
        #pragma unroll
        for (int i = 0; i < 4; ++i)
            #pragma unroll
            for (int j = 0; j < 4; ++j)
                acc[i][j] = fmaf(av[i], be[j], acc[i][j]);
    }

    float* op = out + ((size_t)(b * NN + n0)) * DD + d0;
    #pragma unroll
    for (int i = 0; i < 4; ++i) {
        const float4 v = {acc[i][0], acc[i][1], acc[i][2], acc[i][3]};
        *(float4*)(op + (size_t)(4 * tr + i) * DD + 4 * tc) = v;
    }
}

extern "C" void kernel_launch(void* const* d_in, const int* in_sizes, int n_in,
                              void* d_out, int out_size, void* d_ws, size_t ws_size,
                              hipStream_t stream) {
    const float* X    = (const float*)d_in[0];  // (8,512,512)
    const float* Wqkv = (const float*)d_in[1];  // (512,192)
    const float* Wo   = (const float*)d_in[2];  // (64,512)
    float* out = (float*)d_out;                 // (8,512,512)

    float* qkv  = (float*)d_ws;                 // [w][b][c][n], 3 MB
    float* sa_t = qkv + (size_t)3 * CHN;        // [b][c][n], 1 MB

    qkv_mfma<<<dim3(64, 3), 512, 0, stream>>>(X, Wqkv, qkv);
    attn<<<dim3(BB * DKK), 256, 0, stream>>>(qkv, sa_t);
    out_gemm<<<dim3(64, 8), 256, 0, stream>>>(sa_t, Wo, out);
}